// Round 10
// baseline (171.898 us; speedup 1.0000x reference)
//
#include <hip/hip_runtime.h>

// Problem constants
#define NB 2
#define DD 192
#define HH 192
#define WW 192
#define HWSZ (HH * WW)
#define C1F 0.0001f
#define C2F 0.0009f

// Tiling: 16(H) x 32(W) outputs per block-slice, 256 threads, stream D.
#define TH 16
#define TW 32
#define CHUNK 32
#define TSTEPS (CHUNK + 10)          // 42
#define NCH (DD / CHUNK)             // 6
#define NTH (HH / TH)                // 12
#define NTW (WW / TW)                // 6
#define NBLK (NB * NCH * NTH * NTW)  // 864

#define SROWS (TH + 10)              // 26 staged/W-blurred rows
#define SCOLS 42                     // staged cols (w0-5 .. w0+36)
#define SP2 44                       // s2 row stride in float2 (even -> f4 aligned)
#define TQ 36                        // t4 row stride in quads
#define NSTG (SROWS * SCOLS)         // 1092 stage tasks
#define NWT (SROWS * (TW / 4))       // 208 W-blur tasks

// Gaussian weights, WIN=11, sigma=1.5
#define KWLIST { 0.00102838f, 0.00759876f, 0.03600077f, 0.10936071f, 0.21300556f, \
                 0.26601172f, 0.21300556f, 0.10936071f, 0.03600077f, 0.00759876f, 0.00102838f }

// SSIM from 4 packed stats: mu1, mu2, A=blur((x+y)^2), Bm=blur((x-y)^2).
__device__ __forceinline__ float ssim_val(float mu1, float mu2, float A, float Bm) {
  const float mu1sq = mu1 * mu1, mu2sq = mu2 * mu2, mu12 = mu1 * mu2;
  const float num = (2.f * mu12 + C1F) * (0.5f * (A - Bm) - 2.f * mu12 + C2F);
  const float den = (mu1sq + mu2sq + C1F) * (0.5f * (A + Bm) - mu1sq - mu2sq + C2F);
  return num * __builtin_amdgcn_rcpf(den);
}

__global__ __launch_bounds__(256) void ssim_fused(
    const float* __restrict__ x, const float* __restrict__ y,
    float* __restrict__ partials) {
  const float KW[11] = KWLIST;

  int bid = blockIdx.x;
  const int tw = bid % NTW; bid /= NTW;
  const int th = bid % NTH; bid /= NTH;
  const int c  = bid % NCH; bid /= NCH;
  const int b  = bid;
  const int h0 = th * TH, w0 = tw * TW, c0 = c * CHUNK;

  __shared__ __align__(16) float2 s2[SROWS][SP2];  // staged {x, y} per pixel
  __shared__ float4 t4[SROWS][TQ];   // W-blurred 4 fields (store-rotated layout)

  const int tid = threadIdx.x;
  const int cl  = tid & 31;            // own W col
  const int rg  = tid >> 5;            // 0..7 row-group
  const int r0  = 2 * rg;              // own output rows r0, r0+1
  // t4 store-rotation inverse: pixel cl lives at position
  //   (cl & ~3) | ((cl + (cl>>2)) & 3)
  const int clp2 = (cl & ~3) | (((cl & 3) + (cl >> 2)) & 3);

  // ---- hoisted stage-task addressing: 1092 scalar tasks, 5 rounds ----
  int  sIdx[5], sOff[5];
  bool sOk[5];
#pragma unroll
  for (int k = 0; k < 5; ++k) {
    const int q = tid + 256 * k;
    const bool act = (q < NSTG);
    const int row = q / SCOLS, col = q % SCOLS;
    const int gh = h0 - 5 + row, gw = w0 - 5 + col;
    sOk[k]  = act && (unsigned)gh < (unsigned)HH && (unsigned)gw < (unsigned)WW;
    sIdx[k] = row * SP2 + col;
    sOff[k] = gh * WW + gw;
  }
  // W-blur task addressing (208 tasks); rotated store positions
  const bool wAct = (tid < NWT);
  const int  wr = tid >> 3;            // 0..25
  const int  wq = tid & 7;             // 0..7 (4-output group)
  const int  tBase = wr * TQ + 4 * wq;
  const int  st0 = tBase + ((0 + wq) & 3);
  const int  st1 = tBase + ((1 + wq) & 3);
  const int  st2 = tBase + ((2 + wq) & 3);
  const int  st3 = tBase + ((3 + wq) & 3);

  // zero-init s2 once (OOB cols stay zero all kernel)
  {
    const float2 z = make_float2(0.f, 0.f);
    for (int q = tid; q < SROWS * SP2; q += 256) (&s2[0][0])[q] = z;
  }
  __syncthreads();

  const float* xb = x + (size_t)b * DD * HWSZ;
  const float* yb = y + (size_t)b * DD * HWSZ;

  // Ring accumulators (2 output rows x 4 fields x 11 slots), compile-time idx.
  float pend0[4][11], pend1[4][11];
#pragma unroll
  for (int f = 0; f < 4; ++f)
#pragma unroll
    for (int i = 0; i < 11; ++i) { pend0[f][i] = 0.f; pend1[f][i] = 0.f; }

  float px[5], py[5];
#pragma unroll
  for (int k = 0; k < 5; ++k) { px[k] = 0.f; py[k] = 0.f; }

  // pre-loop prefetch of slice t=0 (d = c0-5), only valid for c>0
  if (c0 >= 5) {
    const float* xs = xb + (size_t)(c0 - 5) * HWSZ;
    const float* ys = yb + (size_t)(c0 - 5) * HWSZ;
#pragma unroll
    for (int k = 0; k < 5; ++k)
      if (sOk[k]) { px[k] = xs[sOff[k]]; py[k] = ys[sOff[k]]; }
  }

  float lsum = 0.f;
  int p = 0;   // t mod 11 (wave-uniform)

  for (int t = 0; t < TSTEPS; ++t) {
    const int d = c0 - 5 + t;
    const bool dv = (d >= 0) && (d < DD);   // block-uniform

    if (dv) {
      // ---- stage prefetched slice ({x,y} only, b64 writes) ----
#pragma unroll
      for (int k = 0; k < 5; ++k)
        if (sOk[k]) (&s2[0][0])[sIdx[k]] = make_float2(px[k], py[k]);
    }
    // ---- prefetch slice t+1 (latency hidden under W/H compute) ----
    {
      const int dn = d + 1;
      if ((t + 1) < TSTEPS && dn >= 0 && dn < DD) {
        const float* xs = xb + (size_t)dn * HWSZ;
        const float* ys = yb + (size_t)dn * HWSZ;
#pragma unroll
        for (int k = 0; k < 5; ++k)
          if (sOk[k]) { px[k] = xs[sOff[k]]; py[k] = ys[sOff[k]]; }
      }
    }

    float4 B0 = make_float4(0.f, 0.f, 0.f, 0.f);
    float4 B1 = B0;

    if (dv) {
      __syncthreads();
      // ---- W-blur: 4 outputs per task; 7 float4 reads = 14 {x,y} pixels;
      //      (x+y)^2, (x-y)^2 computed inline ----
      if (wAct) {
        const float4* srow4 = (const float4*)&s2[wr][0];   // row base 16B-aligned
        float4 a0 = make_float4(0.f, 0.f, 0.f, 0.f), a1 = a0, a2 = a0, a3 = a0;
#pragma unroll
        for (int u2 = 0; u2 < 7; ++u2) {
          const float4 v2 = srow4[2 * wq + u2];   // pixels 4wq+2u2, 4wq+2u2+1
#pragma unroll
          for (int h = 0; h < 2; ++h) {
            const int   u  = 2 * u2 + h;
            const float xx = h ? v2.z : v2.x;
            const float yy = h ? v2.w : v2.y;
            const float sm = xx + yy, df = xx - yy;
            const float s2q = sm * sm, d2q = df * df;
            if (u <= 10)           { const float k = KW[u];     a0.x += k*xx; a0.y += k*yy; a0.z += k*s2q; a0.w += k*d2q; }
            if (u >= 1 && u <= 11) { const float k = KW[u - 1]; a1.x += k*xx; a1.y += k*yy; a1.z += k*s2q; a1.w += k*d2q; }
            if (u >= 2 && u <= 12) { const float k = KW[u - 2]; a2.x += k*xx; a2.y += k*yy; a2.z += k*s2q; a2.w += k*d2q; }
            if (u >= 3)            { const float k = KW[u - 3]; a3.x += k*xx; a3.y += k*yy; a3.z += k*s2q; a3.w += k*d2q; }
          }
        }
        // rotated stores: position 4wq+(i+wq)%4
        float4* tb = &t4[0][0];
        tb[st0] = a0; tb[st1] = a1; tb[st2] = a2; tb[st3] = a3;
      }
      __syncthreads();

      // ---- H-blur: 2 output rows per thread; un-permuted read col clp2 ----
#pragma unroll
      for (int u = 0; u < 12; ++u) {
        const float4 v = t4[r0 + u][clp2];
        if (u <= 10) { const float k = KW[u];     B0.x += k*v.x; B0.y += k*v.y; B0.z += k*v.z; B0.w += k*v.w; }
        if (u >= 1)  { const float k = KW[u - 1]; B1.x += k*v.x; B1.y += k*v.y; B1.z += k*v.z; B1.w += k*v.w; }
      }
    }

    // ---- D-ring: compile-time slots via switch on p = t % 11 ----
#define RING_CASE(P)                                                        \
    case P: {                                                               \
      if (dv) {                                                             \
        _Pragma("unroll")                                                   \
        for (int kk = 0; kk < 11; ++kk) {                                   \
          const int   sl = (P + 1 + kk) % 11;                               \
          const float wg = KW[kk];                                          \
          pend0[0][sl] += wg * B0.x; pend0[1][sl] += wg * B0.y;             \
          pend0[2][sl] += wg * B0.z; pend0[3][sl] += wg * B0.w;             \
          pend1[0][sl] += wg * B1.x; pend1[1][sl] += wg * B1.y;             \
          pend1[2][sl] += wg * B1.z; pend1[3][sl] += wg * B1.w;             \
        }                                                                   \
      }                                                                     \
      const int sc = (P + 1) % 11;                                          \
      if (t >= 10) {                                                        \
        lsum += ssim_val(pend0[0][sc], pend0[1][sc], pend0[2][sc], pend0[3][sc]); \
        lsum += ssim_val(pend1[0][sc], pend1[1][sc], pend1[2][sc], pend1[3][sc]); \
      }                                                                     \
      pend0[0][sc] = 0.f; pend0[1][sc] = 0.f;                               \
      pend0[2][sc] = 0.f; pend0[3][sc] = 0.f;                               \
      pend1[0][sc] = 0.f; pend1[1][sc] = 0.f;                               \
      pend1[2][sc] = 0.f; pend1[3][sc] = 0.f;                               \
    } break;

    switch (p) {
      RING_CASE(0) RING_CASE(1) RING_CASE(2) RING_CASE(3) RING_CASE(4)
      RING_CASE(5) RING_CASE(6) RING_CASE(7) RING_CASE(8) RING_CASE(9)
      RING_CASE(10)
    }
#undef RING_CASE
    p = (p + 1 == 11) ? 0 : p + 1;
  }

  // ---- block reduction: 4 waves ----
  for (int off = 32; off > 0; off >>= 1) lsum += __shfl_down(lsum, off, 64);
  __shared__ float wsum[4];
  if ((tid & 63) == 0) wsum[tid >> 6] = lsum;
  __syncthreads();
  if (tid == 0) partials[blockIdx.x] = wsum[0] + wsum[1] + wsum[2] + wsum[3];
}

// ---------------------------------------------------------------------------
// Final reduction: NBLK partials -> mean (deterministic, double).
// ---------------------------------------------------------------------------
__global__ __launch_bounds__(256) void ssim_reduce(
    const float* __restrict__ partials, float* __restrict__ out) {
  __shared__ double sd[256];
  double a = 0.0;
  for (int i = threadIdx.x; i < NBLK; i += 256) a += (double)partials[i];
  sd[threadIdx.x] = a;
  __syncthreads();
  for (int s = 128; s > 0; s >>= 1) {
    if ((int)threadIdx.x < s) sd[threadIdx.x] += sd[threadIdx.x + s];
    __syncthreads();
  }
  if (threadIdx.x == 0) {
    out[0] = (float)(sd[0] / (double)((size_t)NB * DD * HH * WW));
  }
}

extern "C" void kernel_launch(void* const* d_in, const int* in_sizes, int n_in,
                              void* d_out, int out_size, void* d_ws, size_t ws_size,
                              hipStream_t stream) {
  const float* img1 = (const float*)d_in[0];
  const float* img2 = (const float*)d_in[1];
  float* out = (float*)d_out;
  float* partials = (float*)d_ws;   // NBLK floats

  ssim_fused<<<NBLK, 256, 0, stream>>>(img1, img2, partials);
  ssim_reduce<<<1, 256, 0, stream>>>(partials, out);
}

// Round 11
// 167.450 us; speedup vs baseline: 1.0266x; 1.0266x over previous
//
#include <hip/hip_runtime.h>

// Problem constants
#define NB 2
#define DD 192
#define HH 192
#define WW 192
#define HWSZ (HH * WW)
#define C1F 0.0001f
#define C2F 0.0009f

// Tiling: 16(H) x 32(W) outputs per block-slice, 256 threads, stream D.
#define TH 16
#define TW 32
#define CHUNK 32
#define TSTEPS (CHUNK + 10)          // 42
#define NCH (DD / CHUNK)             // 6
#define NTH (HH / TH)                // 12
#define NTW (WW / TW)                // 6
#define NBLK (NB * NCH * NTH * NTW)  // 864

#define SROWS (TH + 10)              // 26 staged/W-blurred rows
#define SCOLS 42                     // staged cols (w0-5 .. w0+36)
#define SP2 44                       // s2 row stride in float2
#define TQ 36                        // t4 row stride in quads
#define NSTG (SROWS * SCOLS)         // 1092 stage tasks
#define NWT (SROWS * (TW / 4))       // 208 W-blur tasks

// Gaussian weights, WIN=11, sigma=1.5
#define KWLIST { 0.00102838f, 0.00759876f, 0.03600077f, 0.10936071f, 0.21300556f, \
                 0.26601172f, 0.21300556f, 0.10936071f, 0.03600077f, 0.00759876f, 0.00102838f }

// SSIM from 4 packed stats: mu1, mu2, A=blur((x+y)^2), Bm=blur((x-y)^2).
__device__ __forceinline__ float ssim_val(float mu1, float mu2, float A, float Bm) {
  const float mu1sq = mu1 * mu1, mu2sq = mu2 * mu2, mu12 = mu1 * mu2;
  const float num = (2.f * mu12 + C1F) * (0.5f * (A - Bm) - 2.f * mu12 + C2F);
  const float den = (mu1sq + mu2sq + C1F) * (0.5f * (A + Bm) - mu1sq - mu2sq + C2F);
  return num * __builtin_amdgcn_rcpf(den);
}

// Software-pipelined fused SSIM: per phase (ONE barrier) run three independent
// streams: H+ring of slice e (t4[cb]), W-blur of slice e+1 (s2[cb]->t4[nb]),
// stage of slice e+2 (->s2[nb]) + prefetch of slice e+3 into registers.
__global__ __launch_bounds__(256) void ssim_fused(
    const float* __restrict__ x, const float* __restrict__ y,
    float* __restrict__ partials) {
  const float KW[11] = KWLIST;

  int bid = blockIdx.x;
  const int tw = bid % NTW; bid /= NTW;
  const int th = bid % NTH; bid /= NTH;
  const int c  = bid % NCH; bid /= NCH;
  const int b  = bid;
  const int h0 = th * TH, w0 = tw * TW, c0 = c * CHUNK;

  // Double-buffered LDS. s2 odd rows shifted by 2 float2 (4 words) so the
  // W-blur float4 reads cover all 8 bank-groups (conflict-free).
  __shared__ __align__(16) float2 s2[2][SROWS][SP2];  // staged {x, y}
  __shared__ float4 t4[2][SROWS][TQ];                 // W-blurred 4 fields

  const int tid = threadIdx.x;
  const int cl  = tid & 31;            // own W col
  const int rg  = tid >> 5;            // 0..7 row-group
  const int r0  = 2 * rg;              // own output rows r0, r0+1
  // t4 store-rotation inverse: pixel cl lives at (cl&~3)|((cl+(cl>>2))&3)
  const int clp2 = (cl & ~3) | (((cl & 3) + (cl >> 2)) & 3);

  // ---- hoisted stage-task addressing: 1092 scalar tasks, 5 rounds ----
  int  sIdx[5], sOff[5];
  bool sOk[5];
#pragma unroll
  for (int k = 0; k < 5; ++k) {
    const int q = tid + 256 * k;
    const bool act = (q < NSTG);
    const int row = q / SCOLS, col = q % SCOLS;
    const int gh = h0 - 5 + row, gw = w0 - 5 + col;
    sOk[k]  = act && (unsigned)gh < (unsigned)HH && (unsigned)gw < (unsigned)WW;
    sIdx[k] = row * SP2 + 2 * (row & 1) + col;   // odd-row shift
    sOff[k] = gh * WW + gw;
  }
  // W-blur task addressing (208 tasks); rotated store positions
  const bool wAct = (tid < NWT);
  const int  wr = tid >> 3;            // 0..25
  const int  wq = tid & 7;             // 0..7 (4-output group)
  const int  tBase = wr * TQ + 4 * wq;
  const int  st0 = tBase + ((0 + wq) & 3);
  const int  st1 = tBase + ((1 + wq) & 3);
  const int  st2 = tBase + ((2 + wq) & 3);
  const int  st3 = tBase + ((3 + wq) & 3);

  // zero-init both s2 buffers (OOB cols + shift pads stay zero all kernel)
  {
    const float2 z = make_float2(0.f, 0.f);
    float2* sb = &s2[0][0][0];
    for (int q = tid; q < 2 * SROWS * SP2; q += 256) sb[q] = z;
  }

  const float* xb = x + (size_t)b * DD * HWSZ;
  const float* yb = y + (size_t)b * DD * HWSZ;

  float px[5], py[5];
#pragma unroll
  for (int k = 0; k < 5; ++k) { px[k] = 0.f; py[k] = 0.f; }

  auto do_prefetch = [&](int g) {
    const float* xs = xb + (size_t)g * HWSZ;
    const float* ys = yb + (size_t)g * HWSZ;
#pragma unroll
    for (int k = 0; k < 5; ++k)
      if (sOk[k]) { px[k] = xs[sOff[k]]; py[k] = ys[sOff[k]]; }
  };
  auto do_stage = [&](float2* s2buf) {
#pragma unroll
    for (int k = 0; k < 5; ++k)
      if (sOk[k]) s2buf[sIdx[k]] = make_float2(px[k], py[k]);
  };
  auto do_wblur = [&](const float2* s2buf, float4* t4buf) {
    if (wAct) {
      const float4* srow4 = (const float4*)(s2buf + wr * SP2 + 2 * (wr & 1));
      float4 a0 = make_float4(0.f, 0.f, 0.f, 0.f), a1 = a0, a2 = a0, a3 = a0;
#pragma unroll
      for (int u2 = 0; u2 < 7; ++u2) {
        const float4 v2 = srow4[2 * wq + u2];   // pixels 4wq+2u2, +1
#pragma unroll
        for (int h = 0; h < 2; ++h) {
          const int   u  = 2 * u2 + h;
          const float xx = h ? v2.z : v2.x;
          const float yy = h ? v2.w : v2.y;
          const float sm = xx + yy, df = xx - yy;
          const float sq = sm * sm, dq = df * df;
          if (u <= 10)           { const float k = KW[u];     a0.x += k*xx; a0.y += k*yy; a0.z += k*sq; a0.w += k*dq; }
          if (u >= 1 && u <= 11) { const float k = KW[u - 1]; a1.x += k*xx; a1.y += k*yy; a1.z += k*sq; a1.w += k*dq; }
          if (u >= 2 && u <= 12) { const float k = KW[u - 2]; a2.x += k*xx; a2.y += k*yy; a2.z += k*sq; a2.w += k*dq; }
          if (u >= 3)            { const float k = KW[u - 3]; a3.x += k*xx; a3.y += k*yy; a3.z += k*sq; a3.w += k*dq; }
        }
      }
      t4buf[st0] = a0; t4buf[st1] = a1; t4buf[st2] = a2; t4buf[st3] = a3;
    }
  };

  // Ring accumulators (2 rows x 4 fields x 11 slots), compile-time idx.
  float pend0[4][11], pend1[4][11];
#pragma unroll
  for (int f = 0; f < 4; ++f)
#pragma unroll
    for (int i = 0; i < 11; ++i) { pend0[f][i] = 0.f; pend1[f][i] = 0.f; }

  float lsum = 0.f;

  // ---- prologue ----
  __syncthreads();                       // init -> stage
  if (c0 - 5 >= 0) do_prefetch(c0 - 5);
  if (c0 - 5 >= 0) do_stage(&s2[1][0][0]);       // slice c0-5 -> s2[1]
  if (c0 - 4 >= 0) do_prefetch(c0 - 4);
  __syncthreads();
  if (c0 - 5 >= 0) do_wblur(&s2[1][0][0], &t4[0][0][0]);  // W(c0-5) -> t4[0]
  if (c0 - 4 >= 0) do_stage(&s2[0][0][0]);       // slice c0-4 -> s2[0]
  if (c0 - 3 >= 0) do_prefetch(c0 - 3);
  __syncthreads();

  int p = 0;   // j mod 11 (wave-uniform)
  for (int j = 0; j < TSTEPS; ++j) {
    const int cb = j & 1, nb = cb ^ 1;
    const int e = c0 - 5 + j;            // slice for H+ring (t4[cb])
    const int d = e + 1;                 // slice for W (s2[cb] -> t4[nb])
    const int g = e + 2;                 // slice to stage (-> s2[nb])
    const bool eOK = (e >= 0) && (e < DD);
    const bool dOK = (j <= 40) && (d >= 0) && (d < DD);
    const bool gOK = (j <= 39) && (g >= 0) && (g < DD);
    const bool g2OK = (j <= 38) && (g + 1 >= 0) && (g + 1 < DD);

    // 1. stage prefetched slice g into s2[nb]
    if (gOK) do_stage(&s2[nb][0][0]);
    // 2. issue prefetch of slice g+1 (lands during W/H below)
    if (g2OK) do_prefetch(g + 1);
    // 3. W-blur slice d: s2[cb] -> t4[nb]
    if (dOK) do_wblur(&s2[cb][0][0], &t4[nb][0][0]);

    // 4. H-blur + ring for slice e from t4[cb]
    float4 B0 = make_float4(0.f, 0.f, 0.f, 0.f);
    float4 B1 = B0;
    if (eOK) {
      const float4* tb = &t4[cb][0][0];
#pragma unroll
      for (int u = 0; u < 12; ++u) {
        const float4 v = tb[(r0 + u) * TQ + clp2];
        if (u <= 10) { const float k = KW[u];     B0.x += k*v.x; B0.y += k*v.y; B0.z += k*v.z; B0.w += k*v.w; }
        if (u >= 1)  { const float k = KW[u - 1]; B1.x += k*v.x; B1.y += k*v.y; B1.z += k*v.z; B1.w += k*v.w; }
      }
    }

#define RING_CASE(P)                                                        \
    case P: {                                                               \
      if (eOK) {                                                            \
        _Pragma("unroll")                                                   \
        for (int kk = 0; kk < 11; ++kk) {                                   \
          const int   sl = (P + 1 + kk) % 11;                               \
          const float wg = KW[kk];                                          \
          pend0[0][sl] += wg * B0.x; pend0[1][sl] += wg * B0.y;             \
          pend0[2][sl] += wg * B0.z; pend0[3][sl] += wg * B0.w;             \
          pend1[0][sl] += wg * B1.x; pend1[1][sl] += wg * B1.y;             \
          pend1[2][sl] += wg * B1.z; pend1[3][sl] += wg * B1.w;             \
        }                                                                   \
      }                                                                     \
      const int sc = (P + 1) % 11;                                          \
      if (j >= 10) {                                                        \
        lsum += ssim_val(pend0[0][sc], pend0[1][sc], pend0[2][sc], pend0[3][sc]); \
        lsum += ssim_val(pend1[0][sc], pend1[1][sc], pend1[2][sc], pend1[3][sc]); \
      }                                                                     \
      pend0[0][sc] = 0.f; pend0[1][sc] = 0.f;                               \
      pend0[2][sc] = 0.f; pend0[3][sc] = 0.f;                               \
      pend1[0][sc] = 0.f; pend1[1][sc] = 0.f;                               \
      pend1[2][sc] = 0.f; pend1[3][sc] = 0.f;                               \
    } break;

    switch (p) {
      RING_CASE(0) RING_CASE(1) RING_CASE(2) RING_CASE(3) RING_CASE(4)
      RING_CASE(5) RING_CASE(6) RING_CASE(7) RING_CASE(8) RING_CASE(9)
      RING_CASE(10)
    }
#undef RING_CASE
    p = (p + 1 == 11) ? 0 : p + 1;

    // 5. single barrier per step
    __syncthreads();
  }

  // ---- block reduction: 4 waves ----
  for (int off = 32; off > 0; off >>= 1) lsum += __shfl_down(lsum, off, 64);
  __shared__ float wsum[4];
  if ((tid & 63) == 0) wsum[tid >> 6] = lsum;
  __syncthreads();
  if (tid == 0) partials[blockIdx.x] = wsum[0] + wsum[1] + wsum[2] + wsum[3];
}

// ---------------------------------------------------------------------------
// Final reduction: NBLK partials -> mean (deterministic, double).
// ---------------------------------------------------------------------------
__global__ __launch_bounds__(256) void ssim_reduce(
    const float* __restrict__ partials, float* __restrict__ out) {
  __shared__ double sd[256];
  double a = 0.0;
  for (int i = threadIdx.x; i < NBLK; i += 256) a += (double)partials[i];
  sd[threadIdx.x] = a;
  __syncthreads();
  for (int s = 128; s > 0; s >>= 1) {
    if ((int)threadIdx.x < s) sd[threadIdx.x] += sd[threadIdx.x + s];
    __syncthreads();
  }
  if (threadIdx.x == 0) {
    out[0] = (float)(sd[0] / (double)((size_t)NB * DD * HH * WW));
  }
}

extern "C" void kernel_launch(void* const* d_in, const int* in_sizes, int n_in,
                              void* d_out, int out_size, void* d_ws, size_t ws_size,
                              hipStream_t stream) {
  const float* img1 = (const float*)d_in[0];
  const float* img2 = (const float*)d_in[1];
  float* out = (float*)d_out;
  float* partials = (float*)d_ws;   // NBLK floats

  ssim_fused<<<NBLK, 256, 0, stream>>>(img1, img2, partials);
  ssim_reduce<<<1, 256, 0, stream>>>(partials, out);
}